// Round 8
// baseline (58.994 us; speedup 1.0000x reference)
//
#include <hip/hip_runtime.h>

// LengthRegulator fused, scatter-based (R6 structure, best known 51.5us),
// single change: plain stores instead of nontemporal (A/B test).
// B=32, T=512, D=512, t_out=4096. Grid = (512, 32), 256 thr.

#define T_PH 512
#define FPB  8   // frames per block

typedef float f32x4 __attribute__((ext_vector_type(4)));

__global__ __launch_bounds__(256) void lr_fused_kernel(
    const f32x4* __restrict__ enc,   // [B, T, 128]
    const int*   __restrict__ dur,   // [B, T]
    f32x4*       __restrict__ out,   // [B, t_out, 128]
    int t_out) {

    __shared__ int wtot[4];        // per-wave totals
    __shared__ int idxs[FPB];      // source phoneme per frame (-1 = pad)

    const int tid  = threadIdx.x;  // 0..255
    const int wav  = tid >> 6;     // 0..3
    const int lane = tid & 63;
    const int b    = blockIdx.y;
    const int j0   = blockIdx.x * FPB;

    // --- load dur row (2 ints/thread, coalesced) ---
    int2 d2 = ((const int2*)(dur + b * T_PH))[tid];
    int v0 = (d2.x < 1) ? 1 : d2.x;
    int v1 = (d2.y < 1) ? 1 : d2.y;
    int p  = v0 + v1;

    // --- wave-level inclusive scan of pair sums (register-only) ---
    #pragma unroll
    for (int off = 1; off < 64; off <<= 1) {
        int t = __shfl_up(p, off);
        if (lane >= off) p += t;
    }
    if (lane == 63) wtot[wav] = p;
    if (tid < FPB) idxs[tid] = -1;   // pad default
    __syncthreads();

    // --- add preceding-wave totals ---
    int wbase = 0;
    #pragma unroll
    for (int w = 0; w < 3; ++w)
        wbase += (wav > w) ? wtot[w] : 0;
    int S = wbase + p;               // inclusive cumsum through pair elem 1

    // --- scatter: phoneme 2*tid covers [S-v1-v0, S-v1), 2*tid+1 [S-v1, S) ---
    {
        int s0 = S - v1 - v0, e0 = S - v1;
        int lo = (s0 > j0) ? s0 : j0;
        int hi = (e0 < j0 + FPB) ? e0 : (j0 + FPB);
        for (int j = lo; j < hi; ++j) idxs[j - j0] = 2 * tid;
        int s1 = e0, e1 = S;
        lo = (s1 > j0) ? s1 : j0;
        hi = (e1 < j0 + FPB) ? e1 : (j0 + FPB);
        for (int j = lo; j < hi; ++j) idxs[j - j0] = 2 * tid + 1;
    }
    __syncthreads();

    // --- bandwidth phase: lane128 = f32x4 col, fh = frame parity ---
    const int lane128 = tid & 127;
    const int fh      = tid >> 7;  // 0 or 1

    const f32x4* __restrict__ encb = enc + (size_t)b * T_PH * 128;
    f32x4* __restrict__ outb = out + ((size_t)b * t_out + j0) * 128 + lane128;

    const f32x4 zero = {0.f, 0.f, 0.f, 0.f};

    int p0 = idxs[fh + 0];
    int p1 = idxs[fh + 2];
    int p2 = idxs[fh + 4];
    int p3 = idxs[fh + 6];

    f32x4 w0 = (p0 >= 0) ? encb[(size_t)p0 * 128 + lane128] : zero;
    f32x4 w1 = (p1 >= 0) ? encb[(size_t)p1 * 128 + lane128] : zero;
    f32x4 w2 = (p2 >= 0) ? encb[(size_t)p2 * 128 + lane128] : zero;
    f32x4 w3 = (p3 >= 0) ? encb[(size_t)p3 * 128 + lane128] : zero;

    outb[(size_t)(fh + 0) * 128] = w0;
    outb[(size_t)(fh + 2) * 128] = w1;
    outb[(size_t)(fh + 4) * 128] = w2;
    outb[(size_t)(fh + 6) * 128] = w3;
}

extern "C" void kernel_launch(void* const* d_in, const int* in_sizes, int n_in,
                              void* d_out, int out_size, void* d_ws, size_t ws_size,
                              hipStream_t stream) {
    const float* enc = (const float*)d_in[0];
    const int* dur   = (const int*)d_in[1];
    float* out       = (float*)d_out;

    const int BT = in_sizes[1];           // B*T = 16384
    const int T  = T_PH;                  // 512 (reference setup)
    const int B  = BT / T;                // 32
    const int D  = in_sizes[0] / BT;      // 512 (D/4 = 128 hard-coded)
    const int t_out = out_size / (B * D); // 4096

    dim3 grid(t_out / FPB, B);
    lr_fused_kernel<<<grid, 256, 0, stream>>>(
        (const f32x4*)enc, dur, (f32x4*)out, t_out);
}

// Round 9
// 49.872 us; speedup vs baseline: 1.1829x; 1.1829x over previous
//
#include <hip/hip_runtime.h>

// LengthRegulator fused, scatter-based (R6 structure, best 51.5us) + one
// change: XCD-contiguous blockIdx.x swizzle (T1). 512 x-blocks = 8 XCDs x 64.
// XCD k now owns contiguous frames [512k, 512k+512) per batch -> its enc
// working set is one contiguous ~4MB slice (fits one XCD L2), boundary-row
// duplication drops 64x. B=32, T=512, D=512, t_out=4096.

#define T_PH 512
#define FPB  8   // frames per block

typedef float f32x4 __attribute__((ext_vector_type(4)));

__global__ __launch_bounds__(256) void lr_fused_kernel(
    const f32x4* __restrict__ enc,   // [B, T, 128]
    const int*   __restrict__ dur,   // [B, T]
    f32x4*       __restrict__ out,   // [B, t_out, 128]
    int t_out) {

    __shared__ int wtot[4];        // per-wave totals
    __shared__ int idxs[FPB];      // source phoneme per frame (-1 = pad)

    const int tid  = threadIdx.x;  // 0..255
    const int wav  = tid >> 6;     // 0..3
    const int lane = tid & 63;
    const int b    = blockIdx.y;

    // XCD-contiguous swizzle: linear block id % 8 = blockIdx.x % 8 selects the
    // XCD (gridDim.x = 512 divisible by 8). Map XCD k -> contiguous chunk k.
    const int xb = ((blockIdx.x & 7) << 6) | (blockIdx.x >> 3);  // bijective on [0,512)
    const int j0 = xb * FPB;

    // --- load dur row (2 ints/thread, coalesced) ---
    int2 d2 = ((const int2*)(dur + b * T_PH))[tid];
    int v0 = (d2.x < 1) ? 1 : d2.x;
    int v1 = (d2.y < 1) ? 1 : d2.y;
    int p  = v0 + v1;

    // --- wave-level inclusive scan of pair sums (register-only) ---
    #pragma unroll
    for (int off = 1; off < 64; off <<= 1) {
        int t = __shfl_up(p, off);
        if (lane >= off) p += t;
    }
    if (lane == 63) wtot[wav] = p;
    if (tid < FPB) idxs[tid] = -1;   // pad default
    __syncthreads();

    // --- add preceding-wave totals ---
    int wbase = 0;
    #pragma unroll
    for (int w = 0; w < 3; ++w)
        wbase += (wav > w) ? wtot[w] : 0;
    int S = wbase + p;               // inclusive cumsum through pair elem 1

    // --- scatter: phoneme 2*tid covers [S-v1-v0, S-v1), 2*tid+1 [S-v1, S) ---
    {
        int s0 = S - v1 - v0, e0 = S - v1;
        int lo = (s0 > j0) ? s0 : j0;
        int hi = (e0 < j0 + FPB) ? e0 : (j0 + FPB);
        for (int j = lo; j < hi; ++j) idxs[j - j0] = 2 * tid;
        int s1 = e0, e1 = S;
        lo = (s1 > j0) ? s1 : j0;
        hi = (e1 < j0 + FPB) ? e1 : (j0 + FPB);
        for (int j = lo; j < hi; ++j) idxs[j - j0] = 2 * tid + 1;
    }
    __syncthreads();

    // --- bandwidth phase: lane128 = f32x4 col, fh = frame parity ---
    const int lane128 = tid & 127;
    const int fh      = tid >> 7;  // 0 or 1

    const f32x4* __restrict__ encb = enc + (size_t)b * T_PH * 128;
    f32x4* __restrict__ outb = out + ((size_t)b * t_out + j0) * 128 + lane128;

    const f32x4 zero = {0.f, 0.f, 0.f, 0.f};

    int p0 = idxs[fh + 0];
    int p1 = idxs[fh + 2];
    int p2 = idxs[fh + 4];
    int p3 = idxs[fh + 6];

    f32x4 w0 = (p0 >= 0) ? encb[(size_t)p0 * 128 + lane128] : zero;
    f32x4 w1 = (p1 >= 0) ? encb[(size_t)p1 * 128 + lane128] : zero;
    f32x4 w2 = (p2 >= 0) ? encb[(size_t)p2 * 128 + lane128] : zero;
    f32x4 w3 = (p3 >= 0) ? encb[(size_t)p3 * 128 + lane128] : zero;

    __builtin_nontemporal_store(w0, &outb[(size_t)(fh + 0) * 128]);
    __builtin_nontemporal_store(w1, &outb[(size_t)(fh + 2) * 128]);
    __builtin_nontemporal_store(w2, &outb[(size_t)(fh + 4) * 128]);
    __builtin_nontemporal_store(w3, &outb[(size_t)(fh + 6) * 128]);
}

extern "C" void kernel_launch(void* const* d_in, const int* in_sizes, int n_in,
                              void* d_out, int out_size, void* d_ws, size_t ws_size,
                              hipStream_t stream) {
    const float* enc = (const float*)d_in[0];
    const int* dur   = (const int*)d_in[1];
    float* out       = (float*)d_out;

    const int BT = in_sizes[1];           // B*T = 16384
    const int T  = T_PH;                  // 512 (reference setup)
    const int B  = BT / T;                // 32
    const int D  = in_sizes[0] / BT;      // 512 (D/4 = 128 hard-coded)
    const int t_out = out_size / (B * D); // 4096

    dim3 grid(t_out / FPB, B);
    lr_fused_kernel<<<grid, 256, 0, stream>>>(
        (const f32x4*)enc, dur, (f32x4*)out, t_out);
}